// Round 1
// baseline (412.894 us; speedup 1.0000x reference)
//
#include <hip/hip_runtime.h>
#include <cmath>
#include <utility>

#define DI __device__ __forceinline__

typedef __attribute__((ext_vector_type(8))) short  short8;
typedef __attribute__((ext_vector_type(4))) float  f32x4;

// ===================== constexpr Wigner-3j machinery (mirrors reference) =====================
constexpr double cfact(int n){ double r=1.0; for(int i=2;i<=n;++i) r*=(double)i; return r; }
constexpr double csqrt(double x){ if(x<=0.0) return 0.0; double g = x>1.0?x:1.0; for(int i=0;i<100;++i) g = 0.5*(g + x/g); return g; }
constexpr double csgn(int k){ int m = k%2; if(m<0) m+=2; return m? -1.0:1.0; }
constexpr int cmax3(int a,int b,int c){ int m=a>b?a:b; return m>c?m:c; }
constexpr int cmin3(int a,int b,int c){ int m=a<b?a:b; return m<c?m:c; }

struct cplx { double r, i; };
constexpr cplx cmul(cplx a, cplx b){ return cplx{a.r*b.r - a.i*b.i, a.r*b.i + a.i*b.r}; }
constexpr cplx cadd(cplx a, cplx b){ return cplx{a.r+b.r, a.i+b.i}; }
constexpr cplx cscale(cplx a, double s){ return cplx{a.r*s, a.i*s}; }
constexpr cplx cconj(cplx a){ return cplx{a.r, -a.i}; }

constexpr double su2_cg(int j1,int m1,int j2,int m2,int j3,int m3){
  if (m3 != m1+m2) return 0.0;
  const int vmin = cmax3(-j1+j2+m3, -j1+m1, 0);
  const int vmax = cmin3(j2+j3+m1, j3-j1+j2, j3+m3);
  const double c = csqrt((2.0*j3+1.0) * cfact(j3+j1-j2)*cfact(j3-j1+j2)*cfact(j1+j2-j3)/cfact(j1+j2+j3+1)
                         * cfact(j3+m3)*cfact(j3-m3)
                         / (cfact(j1+m1)*cfact(j1-m1)*cfact(j2+m2)*cfact(j2-m2)));
  double s = 0.0;
  for (int v=vmin; v<=vmax; ++v){
    s += csgn(v+j2+m2)/cfact(v)*cfact(j2+j3+m1-v)*cfact(j1-m1+v)
         /cfact(j3-j1+j2-v)/cfact(j3+m3-v)/cfact(v+j1-j2-m3);
  }
  return c*s;
}

template<int L> struct QM { cplx v[2*L+1][2*L+1]; };
template<int L> constexpr QM<L> qmat(){
  QM<L> q{};
  const double is2 = 0.70710678118654752440;
  for (int m=-L; m<0; ++m){
    q.v[L+m][L-m] = cplx{is2, 0.0};     // col l+|m|
    q.v[L+m][L+m] = cplx{0.0, -is2};    // col l-|m|
  }
  q.v[L][L] = cplx{1.0, 0.0};
  for (int m=1; m<=L; ++m){
    const double sg = (m%2)? -1.0 : 1.0;
    q.v[L+m][L+m] = cplx{sg*is2, 0.0};
    q.v[L+m][L-m] = cplx{0.0, sg*is2};
  }
  const cplx ph = (L%4==0)?cplx{1,0} : (L%4==1)?cplx{0,-1} : (L%4==2)?cplx{-1,0} : cplx{0,1};
  for (int a=0;a<2*L+1;++a) for(int b=0;b<2*L+1;++b) q.v[a][b] = cmul(ph, q.v[a][b]);
  return q;
}

template<int L1,int L2,int L3> struct W3J { float v[2*L1+1][2*L2+1][2*L3+1]; };

template<int L1,int L2,int L3> constexpr W3J<L1,L2,L3> w3j(){
  constexpr int N1=2*L1+1, N2=2*L2+1, N3=2*L3+1;
  double C[N1][N2][N3] = {};
  for (int m1=-L1;m1<=L1;++m1) for (int m2=-L2;m2<=L2;++m2){
    const int m3=m1+m2;
    if (m3>=-L3 && m3<=L3) C[L1+m1][L2+m2][L3+m3] = su2_cg(L1,m1,L2,m2,L3,m3);
  }
  const QM<L1> q1 = qmat<L1>(); const QM<L2> q2 = qmat<L2>(); const QM<L3> q3 = qmat<L3>();
  cplx T1[N1][N2][N3] = {};
  for(int j=0;j<N1;++j) for(int k=0;k<N2;++k) for(int m=0;m<N3;++m){
    cplx acc{0,0};
    for(int i=0;i<N1;++i) acc = cadd(acc, cscale(q1.v[i][j], C[i][k][m]));
    T1[j][k][m]=acc;
  }
  cplx T2[N1][N2][N3] = {};
  for(int j=0;j<N1;++j) for(int l=0;l<N2;++l) for(int m=0;m<N3;++m){
    cplx acc{0,0};
    for(int k=0;k<N2;++k) acc = cadd(acc, cmul(q2.v[k][l], T1[j][k][m]));
    T2[j][l][m]=acc;
  }
  double O[N1][N2][N3] = {};
  double fro = 0.0;
  for(int j=0;j<N1;++j) for(int l=0;l<N2;++l) for(int n=0;n<N3;++n){
    cplx acc{0,0};
    for(int m=0;m<N3;++m) acc = cadd(acc, cmul(cconj(q3.v[m][n]), T2[j][l][m]));
    O[j][l][n] = acc.r;
    fro += acc.r*acc.r;
  }
  const double inv = 1.0/csqrt(fro);
  W3J<L1,L2,L3> w{};
  for(int j=0;j<N1;++j) for(int l=0;l<N2;++l) for(int n=0;n<N3;++n)
    w.v[j][l][n] = (float)(O[j][l][n]*inv);
  return w;
}

constexpr auto CG_000 = w3j<0,0,0>();
constexpr auto CG_110 = w3j<1,1,0>();
constexpr auto CG_220 = w3j<2,2,0>();
constexpr auto CG_011 = w3j<0,1,1>();
constexpr auto CG_101 = w3j<1,0,1>();
constexpr auto CG_121 = w3j<1,2,1>();
constexpr auto CG_211 = w3j<2,1,1>();
constexpr auto CG_321 = w3j<3,2,1>();
constexpr auto CG_022 = w3j<0,2,2>();
constexpr auto CG_112 = w3j<1,1,2>();
constexpr auto CG_202 = w3j<2,0,2>();
constexpr auto CG_222 = w3j<2,2,2>();
constexpr auto CG_312 = w3j<3,1,2>();
constexpr auto CG_213 = w3j<2,1,3>();   // SH recursion l=2 -> l=3

struct ShS { double s0, s1; };
constexpr ShS sh_scales(){
  const double n0=0.3,n1=0.5,n2=0.81;
  const double nn = csqrt(n0*n0+n1*n1+n2*n2);
  const double ny[3] = {n1/nn, n2/nn, n0/nn};
  const double sq3 = csqrt(3.0);
  double Y1[3]; for(int i=0;i<3;++i) Y1[i] = sq3*ny[i];
  double A[5] = {};
  for(int i=0;i<3;++i) for(int j=0;j<3;++j) for(int k=0;k<5;++k)
    A[k] += Y1[i]*ny[j]*(double)CG_112.v[i][j][k];
  double na=0; for(int k=0;k<5;++k) na += A[k]*A[k]; na = csqrt(na);
  const double s0 = csqrt(5.0)/na;
  double Y2[5]; for(int k=0;k<5;++k) Y2[k] = A[k]*s0;
  double B[7] = {};
  for(int i=0;i<5;++i) for(int j=0;j<3;++j) for(int k=0;k<7;++k)
    B[k] += Y2[i]*ny[j]*(double)CG_213.v[i][j][k];
  double nb=0; for(int k=0;k<7;++k) nb += B[k]*B[k]; nb = csqrt(nb);
  const double s1 = csqrt(7.0)/nb;
  return ShS{s0,s1};
}
constexpr ShS SHS = sh_scales();

// ===================== static-for + zero-skipping contraction =====================
template<typename F, int... Is>
DI void sfor_impl(F&& f, std::integer_sequence<int, Is...>){ (f(std::integral_constant<int,Is>{}), ...); }
template<int N, typename F>
DI void sfor(F&& f){ sfor_impl(f, std::make_integer_sequence<int, N>{}); }

template<int N>
__host__ __device__ constexpr bool col_any(const float (&c)[N]){
  for(int k=0;k<N;++k) if (c[k]!=0.0f) return true;
  return false;
}

// OUT[k] += SCALE * TAB[i][j][k] * INI[i] * INJ[j]   (zeros folded away at compile time)
#define CONTRACT3(TAB, NI, NJ, NK, SCALE, INI, INJ, OUT) \
  sfor<(NI)>([&](auto I__){ constexpr int i__ = decltype(I__)::value; \
    sfor<(NJ)>([&](auto J__){ constexpr int j__ = decltype(J__)::value; \
      if constexpr (col_any((TAB).v[i__][j__])) { \
        const float t__ = (INI)[i__] * (INJ)[j__]; \
        sfor<(NK)>([&](auto K__){ constexpr int k__ = decltype(K__)::value; \
          if constexpr ((TAB).v[i__][j__][k__] != 0.0f) { \
            constexpr float c__ = (float)((double)(TAB).v[i__][j__][k__] * (double)(SCALE)); \
            (OUT)[k__] = fmaf(c__, t__, (OUT)[k__]); \
          } }); } }); });

// ===================== device helpers =====================
DI unsigned short f2bf(float f){            // round-to-nearest-even fp32 -> bf16
  unsigned int u = __float_as_uint(f);
  u += 0x7fffu + ((u >> 16) & 1u);
  return (unsigned short)(u >> 16);
}
DI float silu_n(float z, float c){ return c * (z / (1.0f + __expf(-z))); }

constexpr float SQRT3F        = (float)csqrt(3.0);
constexpr double SQ3D         = csqrt(3.0);
constexpr double SQ5D         = csqrt(5.0);
constexpr float INV_SQRT_XD   = (float)(1.0/csqrt(128.0));
constexpr float INV_SQRT_NEI  = 0.25f;                    // 1/sqrt(16)
constexpr float INV320        = (float)(1.0/csqrt(320.0));

// ===================== K1: w = xW0/sqrt(128), Y(l=0..3), atomic scatter =====================
// node_sum layout: [node][k(16)][u(64)]  (atomics coalesce to 256B per wave instruction)
__global__ __launch_bounds__(256) void k_scatter(
    const float* __restrict__ vectors, const float* __restrict__ x,
    const int* __restrict__ senders, const float* __restrict__ W0,
    float* __restrict__ node_sum)
{
  const int tid = threadIdx.x;
  const int lane = tid & 63;
  const int wv = tid >> 6;
  const int e = __builtin_amdgcn_readfirstlane((int)blockIdx.x*4 + wv);
  const int s = senders[e];

  const float* xr = x + e*128;          // wave-uniform -> scalar loads
  float sum = 0.f;
  #pragma unroll 16
  for (int k=0;k<128;++k) sum = fmaf(xr[k], W0[k*64+lane], sum);
  const float w = sum * INV_SQRT_XD;

  const float vx = vectors[e*3+0], vy = vectors[e*3+1], vz = vectors[e*3+2];
  const float dn = sqrtf(vx*vx+vy*vy+vz*vz);
  const float ny[3] = {vy/dn, vz/dn, vx/dn};   // e3nn y,z,x basis
  float Y[16];
  Y[0] = 1.f; Y[1] = SQRT3F*ny[0]; Y[2] = SQRT3F*ny[1]; Y[3] = SQRT3F*ny[2];
  #pragma unroll
  for (int k=4;k<16;++k) Y[k] = 0.f;
  CONTRACT3(CG_112, 3,3,5, SHS.s0, (Y+1), ny, (Y+4));
  CONTRACT3(CG_213, 5,3,7, SHS.s1, (Y+4), ny, (Y+9));

  float* nsrow = node_sum + s*1024;
  #pragma unroll
  for (int k=0;k<16;++k) atomicAdd(nsrow + k*64 + lane, w*Y[k]);
}

// ===================== K2: gather + CG tensor products + fused bf16 MFMA GEMM =====================
// Per block: 8 edges. A matrix (K=320) staged in LDS as MFMA fragments, 6 M-tiles:
//   ti0: x2 = [x | s0]          rows el=0..7            -> B = W1
//   ti1: v1 rows r=i*8+el, r<16 -> B = Wl1
//   ti2: v1 rows 16..23 (i=2)   -> B = Wl1
//   ti3: v2 rows 0..15  (i2=0,1)-> B = Wl2
//   ti4: v2 rows 16..31 (i2=2,3)-> B = Wl2
//   ti5: v2 rows 32..39 (i2=4)  -> B = Wl2
// Garbage rows (8..15 of ti0/ti2/ti5) only affect their own D rows, which are never stored.
DI void wr_frag(char* AF, int ti, int row, int m, float val){
  const int kt = m >> 5, q = (m >> 3) & 3, j = m & 7;
  *(unsigned short*)(AF + (((ti*10 + kt)*64 + row + (q<<4))<<4) + (j<<1)) = f2bf(val);
}

DI short8 load_bfrag(const float* __restrict__ W, int kt, int nt, int lane){
  const int q = lane >> 4, c = lane & 15;
  const float* src = W + (kt*32 + q*8)*64 + nt*16 + c;
  short8 b;
  #pragma unroll
  for (int j=0;j<8;++j) b[j] = (short)f2bf(src[j*64]);
  return b;
}

__global__ __launch_bounds__(256,2) void k_main(
    const float* __restrict__ vectors, const float* __restrict__ x,
    const float* __restrict__ V, const int* __restrict__ senders,
    const float* __restrict__ W1, const float* __restrict__ W2,
    const float* __restrict__ W3, const float* __restrict__ Wl1,
    const float* __restrict__ Wl2, const float* __restrict__ node_sum,
    float* __restrict__ out_x, float* __restrict__ out_V, float silu_c)
{
  __shared__ __align__(16) char smem[61440];   // 6 tiles * 10 kt * 1KB
  char*  AF  = smem;
  float* h1s = (float*)smem;            // overlay after GEMM (guarded by barriers)
  float* h2s = (float*)(smem + 2048);

  const int tid  = threadIdx.x;
  const int lane = tid & 63;
  const int wv   = tid >> 6;
  const int blk  = blockIdx.x;

  // ---------------- Phase A: gather + tensor products + A-fragment staging ----------------
  for (int rep=0; rep<2; ++rep){
    const int el = wv*2 + rep;
    const int e  = __builtin_amdgcn_readfirstlane(blk*8 + el);
    const int s  = senders[e];
    const int u  = lane;

    float g[16];
    const float* nsrow = node_sum + s*1024;
    #pragma unroll
    for (int k=0;k<16;++k) g[k] = nsrow[k*64+u] * INV_SQRT_NEI;
    float vc[9];
    #pragma unroll
    for (int j=0;j<9;++j) vc[j] = V[e*576 + u*9 + j];

    float s0[3] = {0.f,0.f,0.f};
    float v1o[5][3] = {};
    float v2o[5][5] = {};
    // PATHS_0E
    CONTRACT3(CG_000, 1,1,1, 1.0, (g+0), (vc+0), (&s0[0]));
    CONTRACT3(CG_110, 3,3,1, 1.0, (g+1), (vc+1), (&s0[1]));
    CONTRACT3(CG_220, 5,5,1, 1.0, (g+4), (vc+4), (&s0[2]));
    // PATHS_1O (scale sqrt(3))
    CONTRACT3(CG_011, 1,3,3, SQ3D, (g+0), (vc+1), (v1o[0]));
    CONTRACT3(CG_101, 3,1,3, SQ3D, (g+1), (vc+0), (v1o[1]));
    CONTRACT3(CG_121, 3,5,3, SQ3D, (g+1), (vc+4), (v1o[2]));
    CONTRACT3(CG_211, 5,3,3, SQ3D, (g+4), (vc+1), (v1o[3]));
    CONTRACT3(CG_321, 7,5,3, SQ3D, (g+9), (vc+4), (v1o[4]));
    // PATHS_2E (scale sqrt(5))
    CONTRACT3(CG_022, 1,5,5, SQ5D, (g+0), (vc+4), (v2o[0]));
    CONTRACT3(CG_112, 3,3,5, SQ5D, (g+1), (vc+1), (v2o[1]));
    CONTRACT3(CG_202, 5,1,5, SQ5D, (g+4), (vc+0), (v2o[2]));
    CONTRACT3(CG_222, 5,5,5, SQ5D, (g+4), (vc+4), (v2o[3]));
    CONTRACT3(CG_312, 7,3,5, SQ5D, (g+9), (vc+1), (v2o[4]));

    // x2 row (ti0): first 128 = x, then 192 = s0 at c = 128 + u*3 + p
    wr_frag(AF, 0, el, u,      x[e*128 + u]);
    wr_frag(AF, 0, el, 64 + u, x[e*128 + 64 + u]);
    #pragma unroll
    for (int p=0;p<3;++p) wr_frag(AF, 0, el, 128 + u*3 + p, s0[p]);
    #pragma unroll
    for (int p=0;p<5;++p){
      const int m = u*5 + p;
      #pragma unroll
      for (int i=0;i<3;++i){ const int r = i*8+el; wr_frag(AF, 1+(r>>4), r&15, m, v1o[p][i]); }
      #pragma unroll
      for (int i=0;i<5;++i){ const int r = i*8+el; wr_frag(AF, 3+(r>>4), r&15, m, v2o[p][i]); }
    }
  }
  __syncthreads();

  // ---------------- GEMM: D = A(6 tiles x K320) * [W1|Wl1|Wl2], N-tile = wave ----------------
  f32x4 acc0={0.f,0.f,0.f,0.f}, acc1=acc0, acc2=acc0, acc3=acc0, acc4=acc0, acc5=acc0;
  const int nt = wv;
  for (int kt=0; kt<10; ++kt){
    const short8 b0 = load_bfrag(W1,  kt, nt, lane);
    const short8 b1 = load_bfrag(Wl1, kt, nt, lane);
    const short8 b2 = load_bfrag(Wl2, kt, nt, lane);
    const char* ab = AF + kt*1024 + lane*16;
    const short8 a0 = *(const short8*)(ab);
    const short8 a1 = *(const short8*)(ab + 10240);
    const short8 a2 = *(const short8*)(ab + 20480);
    const short8 a3 = *(const short8*)(ab + 30720);
    const short8 a4 = *(const short8*)(ab + 40960);
    const short8 a5 = *(const short8*)(ab + 51200);
    acc0 = __builtin_amdgcn_mfma_f32_16x16x32_bf16(a0, b0, acc0, 0,0,0);
    acc1 = __builtin_amdgcn_mfma_f32_16x16x32_bf16(a1, b1, acc1, 0,0,0);
    acc2 = __builtin_amdgcn_mfma_f32_16x16x32_bf16(a2, b1, acc2, 0,0,0);
    acc3 = __builtin_amdgcn_mfma_f32_16x16x32_bf16(a3, b2, acc3, 0,0,0);
    acc4 = __builtin_amdgcn_mfma_f32_16x16x32_bf16(a4, b2, acc4, 0,0,0);
    acc5 = __builtin_amdgcn_mfma_f32_16x16x32_bf16(a5, b2, acc5, 0,0,0);
  }
  __syncthreads();   // all waves done reading AF before h1s overlays it

  // ---------------- Epilogue: equivariant stores + h1 into LDS ----------------
  // D layout: row = (lane>>4)*4 + reg, col = lane&15
  const int col = lane & 15, qq = lane >> 4;
  const int u2 = nt*16 + col;
  #pragma unroll
  for (int reg=0; reg<4; ++reg){
    const int row = qq*4 + reg;
    if (row < 8) h1s[row*64 + u2] = silu_n(acc0[reg] * INV320, silu_c);
  }
  #pragma unroll
  for (int reg=0; reg<4; ++reg){
    const int row = qq*4 + reg;
    { const int i = row>>3, el = row&7, e = blk*8+el;
      out_V[e*576 + 64 + u2*3 + i] = acc1[reg] * INV320; }
    if (row < 8){ const int e = blk*8 + row;
      out_V[e*576 + 64 + u2*3 + 2] = acc2[reg] * INV320; }
    { const int i2 = row>>3, el = row&7, e = blk*8+el;
      out_V[e*576 + 256 + u2*5 + i2] = acc3[reg] * INV320; }
    { const int i2 = 2 + (row>>3), el = row&7, e = blk*8+el;
      out_V[e*576 + 256 + u2*5 + i2] = acc4[reg] * INV320; }
    if (row < 8){ const int e = blk*8 + row;
      out_V[e*576 + 256 + u2*5 + 4] = acc5[reg] * INV320; }
  }
  __syncthreads();

  // ---------------- Scalar track: h2 = silu_n(h1 W2 /8), h3 = h2 W3 /8, x_out = env*h3 ----------------
  const int el2 = tid >> 5, jb = tid & 31;
  const int e2  = blk*8 + el2;
  float h2v[2];
  #pragma unroll
  for (int h=0; h<2; ++h){
    const int j = jb + 32*h;
    float sacc = 0.f;
    #pragma unroll 8
    for (int c=0;c<64;++c) sacc = fmaf(h1s[el2*64+c], W2[c*64+j], sacc);
    h2v[h] = silu_n(sacc * 0.125f, silu_c);
  }
  h2s[el2*64 + jb]      = h2v[0];
  h2s[el2*64 + jb + 32] = h2v[1];
  __syncthreads();

  const float vx = vectors[e2*3+0], vy = vectors[e2*3+1], vz = vectors[e2*3+2];
  const float d  = sqrtf(vx*vx + vy*vy + vz*vz);
  const float d3 = d*d*d;
  const float d6 = d3*d3;
  const float env = (d < 1.f) ? (1.f + d6*(-28.f + d*(48.f + d*(-21.f)))) : 0.f;
  #pragma unroll
  for (int h=0; h<2; ++h){
    const int j = jb + 32*h;
    float sacc = 0.f;
    #pragma unroll 8
    for (int c=0;c<64;++c) sacc = fmaf(h2s[el2*64+c], W3[c*64+j], sacc);
    out_x[e2*64 + j]  = env * (sacc * 0.125f);
    out_V[e2*576 + j] = 0.f;             // zeros for the 64x0e slot
  }
}

// ===================== host: normalized-silu constant (computed once at load) =====================
static const float g_silu_c = [](){
  const int N = 200001;
  const double h = 24.0/(double)(N-1);
  double acc = 0.0;
  for (int i=0;i<N;++i){
    const double z = -12.0 + h*(double)i;
    const double phi = std::exp(-z*z/2.0)/std::sqrt(2.0*M_PI);
    const double s = z/(1.0+std::exp(-z));
    const double f = s*s*phi;
    acc += (i==0 || i==N-1) ? 0.5*f : f;
  }
  return (float)(1.0/std::sqrt(acc*h));
}();

extern "C" void kernel_launch(void* const* d_in, const int* in_sizes, int n_in,
                              void* d_out, int out_size, void* d_ws, size_t ws_size,
                              hipStream_t stream) {
  (void)in_sizes; (void)n_in; (void)out_size; (void)ws_size;
  const float* vectors = (const float*)d_in[0];
  const float* x       = (const float*)d_in[1];
  const float* V       = (const float*)d_in[2];
  const int*   senders = (const int*)  d_in[3];
  const float* W0      = (const float*)d_in[4];
  const float* W1      = (const float*)d_in[5];
  const float* W2      = (const float*)d_in[6];
  const float* W3      = (const float*)d_in[7];
  const float* Wl1     = (const float*)d_in[8];
  const float* Wl2     = (const float*)d_in[9];
  float* out_x = (float*)d_out;
  float* out_V = out_x + 32768*64;
  float* node_sum = (float*)d_ws;                       // 2048*1024 floats = 8 MB

  hipMemsetAsync(node_sum, 0, (size_t)2048*1024*sizeof(float), stream);
  k_scatter<<<dim3(32768/4), dim3(256), 0, stream>>>(vectors, x, senders, W0, node_sum);
  k_main<<<dim3(32768/8), dim3(256), 0, stream>>>(vectors, x, V, senders,
                                                  W1, W2, W3, Wl1, Wl2,
                                                  node_sum, out_x, out_V, g_silu_c);
}

// Round 2
// 309.173 us; speedup vs baseline: 1.3355x; 1.3355x over previous
//
#include <hip/hip_runtime.h>
#include <cmath>
#include <utility>

#define DI __device__ __forceinline__

typedef __attribute__((ext_vector_type(8))) short  short8;
typedef __attribute__((ext_vector_type(4))) float  f32x4;

// ===================== constexpr Wigner-3j machinery (mirrors reference) =====================
constexpr double cfact(int n){ double r=1.0; for(int i=2;i<=n;++i) r*=(double)i; return r; }
constexpr double csqrt(double x){ if(x<=0.0) return 0.0; double g = x>1.0?x:1.0; for(int i=0;i<100;++i) g = 0.5*(g + x/g); return g; }
constexpr double csgn(int k){ int m = k%2; if(m<0) m+=2; return m? -1.0:1.0; }
constexpr int cmax3(int a,int b,int c){ int m=a>b?a:b; return m>c?m:c; }
constexpr int cmin3(int a,int b,int c){ int m=a<b?a:b; return m<c?m:c; }

struct cplx { double r, i; };
constexpr cplx cmul(cplx a, cplx b){ return cplx{a.r*b.r - a.i*b.i, a.r*b.i + a.i*b.r}; }
constexpr cplx cadd(cplx a, cplx b){ return cplx{a.r+b.r, a.i+b.i}; }
constexpr cplx cscale(cplx a, double s){ return cplx{a.r*s, a.i*s}; }
constexpr cplx cconj(cplx a){ return cplx{a.r, -a.i}; }

constexpr double su2_cg(int j1,int m1,int j2,int m2,int j3,int m3){
  if (m3 != m1+m2) return 0.0;
  const int vmin = cmax3(-j1+j2+m3, -j1+m1, 0);
  const int vmax = cmin3(j2+j3+m1, j3-j1+j2, j3+m3);
  const double c = csqrt((2.0*j3+1.0) * cfact(j3+j1-j2)*cfact(j3-j1+j2)*cfact(j1+j2-j3)/cfact(j1+j2+j3+1)
                         * cfact(j3+m3)*cfact(j3-m3)
                         / (cfact(j1+m1)*cfact(j1-m1)*cfact(j2+m2)*cfact(j2-m2)));
  double s = 0.0;
  for (int v=vmin; v<=vmax; ++v){
    s += csgn(v+j2+m2)/cfact(v)*cfact(j2+j3+m1-v)*cfact(j1-m1+v)
         /cfact(j3-j1+j2-v)/cfact(j3+m3-v)/cfact(v+j1-j2-m3);
  }
  return c*s;
}

template<int L> struct QM { cplx v[2*L+1][2*L+1]; };
template<int L> constexpr QM<L> qmat(){
  QM<L> q{};
  const double is2 = 0.70710678118654752440;
  for (int m=-L; m<0; ++m){
    q.v[L+m][L-m] = cplx{is2, 0.0};
    q.v[L+m][L+m] = cplx{0.0, -is2};
  }
  q.v[L][L] = cplx{1.0, 0.0};
  for (int m=1; m<=L; ++m){
    const double sg = (m%2)? -1.0 : 1.0;
    q.v[L+m][L+m] = cplx{sg*is2, 0.0};
    q.v[L+m][L-m] = cplx{0.0, sg*is2};
  }
  const cplx ph = (L%4==0)?cplx{1,0} : (L%4==1)?cplx{0,-1} : (L%4==2)?cplx{-1,0} : cplx{0,1};
  for (int a=0;a<2*L+1;++a) for(int b=0;b<2*L+1;++b) q.v[a][b] = cmul(ph, q.v[a][b]);
  return q;
}

template<int L1,int L2,int L3> struct W3J { float v[2*L1+1][2*L2+1][2*L3+1]; };

template<int L1,int L2,int L3> constexpr W3J<L1,L2,L3> w3j(){
  constexpr int N1=2*L1+1, N2=2*L2+1, N3=2*L3+1;
  double C[N1][N2][N3] = {};
  for (int m1=-L1;m1<=L1;++m1) for (int m2=-L2;m2<=L2;++m2){
    const int m3=m1+m2;
    if (m3>=-L3 && m3<=L3) C[L1+m1][L2+m2][L3+m3] = su2_cg(L1,m1,L2,m2,L3,m3);
  }
  const QM<L1> q1 = qmat<L1>(); const QM<L2> q2 = qmat<L2>(); const QM<L3> q3 = qmat<L3>();
  cplx T1[N1][N2][N3] = {};
  for(int j=0;j<N1;++j) for(int k=0;k<N2;++k) for(int m=0;m<N3;++m){
    cplx acc{0,0};
    for(int i=0;i<N1;++i) acc = cadd(acc, cscale(q1.v[i][j], C[i][k][m]));
    T1[j][k][m]=acc;
  }
  cplx T2[N1][N2][N3] = {};
  for(int j=0;j<N1;++j) for(int l=0;l<N2;++l) for(int m=0;m<N3;++m){
    cplx acc{0,0};
    for(int k=0;k<N2;++k) acc = cadd(acc, cmul(q2.v[k][l], T1[j][k][m]));
    T2[j][l][m]=acc;
  }
  double O[N1][N2][N3] = {};
  double fro = 0.0;
  for(int j=0;j<N1;++j) for(int l=0;l<N2;++l) for(int n=0;n<N3;++n){
    cplx acc{0,0};
    for(int m=0;m<N3;++m) acc = cadd(acc, cmul(cconj(q3.v[m][n]), T2[j][l][m]));
    O[j][l][n] = acc.r;
    fro += acc.r*acc.r;
  }
  const double inv = 1.0/csqrt(fro);
  W3J<L1,L2,L3> w{};
  for(int j=0;j<N1;++j) for(int l=0;l<N2;++l) for(int n=0;n<N3;++n)
    w.v[j][l][n] = (float)(O[j][l][n]*inv);
  return w;
}

constexpr auto CG_000 = w3j<0,0,0>();
constexpr auto CG_110 = w3j<1,1,0>();
constexpr auto CG_220 = w3j<2,2,0>();
constexpr auto CG_011 = w3j<0,1,1>();
constexpr auto CG_101 = w3j<1,0,1>();
constexpr auto CG_121 = w3j<1,2,1>();
constexpr auto CG_211 = w3j<2,1,1>();
constexpr auto CG_321 = w3j<3,2,1>();
constexpr auto CG_022 = w3j<0,2,2>();
constexpr auto CG_112 = w3j<1,1,2>();
constexpr auto CG_202 = w3j<2,0,2>();
constexpr auto CG_222 = w3j<2,2,2>();
constexpr auto CG_312 = w3j<3,1,2>();
constexpr auto CG_213 = w3j<2,1,3>();   // SH recursion l=2 -> l=3

struct ShS { double s0, s1; };
constexpr ShS sh_scales(){
  const double n0=0.3,n1=0.5,n2=0.81;
  const double nn = csqrt(n0*n0+n1*n1+n2*n2);
  const double ny[3] = {n1/nn, n2/nn, n0/nn};
  const double sq3 = csqrt(3.0);
  double Y1[3]; for(int i=0;i<3;++i) Y1[i] = sq3*ny[i];
  double A[5] = {};
  for(int i=0;i<3;++i) for(int j=0;j<3;++j) for(int k=0;k<5;++k)
    A[k] += Y1[i]*ny[j]*(double)CG_112.v[i][j][k];
  double na=0; for(int k=0;k<5;++k) na += A[k]*A[k]; na = csqrt(na);
  const double s0 = csqrt(5.0)/na;
  double Y2[5]; for(int k=0;k<5;++k) Y2[k] = A[k]*s0;
  double B[7] = {};
  for(int i=0;i<5;++i) for(int j=0;j<3;++j) for(int k=0;k<7;++k)
    B[k] += Y2[i]*ny[j]*(double)CG_213.v[i][j][k];
  double nb=0; for(int k=0;k<7;++k) nb += B[k]*B[k]; nb = csqrt(nb);
  const double s1 = csqrt(7.0)/nb;
  return ShS{s0,s1};
}
constexpr ShS SHS = sh_scales();

// ===================== static-for + zero-skipping contraction =====================
template<typename F, int... Is>
DI void sfor_impl(F&& f, std::integer_sequence<int, Is...>){ (f(std::integral_constant<int,Is>{}), ...); }
template<int N, typename F>
DI void sfor(F&& f){ sfor_impl(f, std::make_integer_sequence<int, N>{}); }

template<int N>
__host__ __device__ constexpr bool col_any(const float (&c)[N]){
  for(int k=0;k<N;++k) if (c[k]!=0.0f) return true;
  return false;
}

#define CONTRACT3(TAB, NI, NJ, NK, SCALE, INI, INJ, OUT) \
  sfor<(NI)>([&](auto I__){ constexpr int i__ = decltype(I__)::value; \
    sfor<(NJ)>([&](auto J__){ constexpr int j__ = decltype(J__)::value; \
      if constexpr (col_any((TAB).v[i__][j__])) { \
        const float t__ = (INI)[i__] * (INJ)[j__]; \
        sfor<(NK)>([&](auto K__){ constexpr int k__ = decltype(K__)::value; \
          if constexpr ((TAB).v[i__][j__][k__] != 0.0f) { \
            constexpr float c__ = (float)((double)(TAB).v[i__][j__][k__] * (double)(SCALE)); \
            (OUT)[k__] = fmaf(c__, t__, (OUT)[k__]); \
          } }); } }); });

// ===================== device helpers =====================
DI unsigned short f2bf(float f){            // round-to-nearest-even fp32 -> bf16
  unsigned int u = __float_as_uint(f);
  u += 0x7fffu + ((u >> 16) & 1u);
  return (unsigned short)(u >> 16);
}
DI float silu_n(float z, float c){ return c * (z / (1.0f + __expf(-z))); }

constexpr float SQRT3F        = (float)csqrt(3.0);
constexpr double SQ3D         = csqrt(3.0);
constexpr double SQ5D         = csqrt(5.0);
constexpr float INV_SQRT_XD   = (float)(1.0/csqrt(128.0));
constexpr float INV_SQRT_NEI  = 0.25f;                    // 1/sqrt(16)
constexpr float INV320        = (float)(1.0/csqrt(320.0));

constexpr int E_TOT = 32768;
constexpr int NNODE = 2048;

// ===================== K_setup: B-fragment precompute (blocks 0..29) + sender histogram =====================
__global__ __launch_bounds__(256) void k_setup(
    const int* __restrict__ senders, int* __restrict__ pos, int* __restrict__ cnt,
    const float* __restrict__ W1, const float* __restrict__ Wl1, const float* __restrict__ Wl2,
    short8* __restrict__ bfrag)
{
  const int blk = blockIdx.x;
  if (blk < 30){
    if (bfrag == nullptr) return;
    const int wv = threadIdx.x >> 6, lane = threadIdx.x & 63;
    const int wid = blk*4 + wv;                   // 0..119 = (mat,kt,nt)
    const int mat = wid/40, r = wid%40, kt = r>>2, nt = r&3;
    const float* W = (mat==0)?W1 : (mat==1)?Wl1 : Wl2;
    const int q = lane>>4, c = lane&15;
    const float* src = W + (kt*32 + q*8)*64 + nt*16 + c;
    short8 b;
    #pragma unroll
    for (int j=0;j<8;++j) b[j] = (short)f2bf(src[j*64]);
    bfrag[wid*64 + lane] = b;
  } else {
    const int e = (blk-30)*256 + threadIdx.x;
    if (e < E_TOT) pos[e] = atomicAdd(&cnt[senders[e]], 1);
  }
}

// ===================== K_scan: exclusive prefix over 2048 counts (1 block) =====================
__global__ __launch_bounds__(256) void k_scan(const int* __restrict__ cnt, int* __restrict__ off)
{
  __shared__ int ts[256];
  const int t = threadIdx.x;
  int loc[8]; int s = 0;
  #pragma unroll
  for (int i=0;i<8;++i){ int v = cnt[t*8+i]; loc[i] = s; s += v; }   // loc = within-thread exclusive
  ts[t] = s;
  __syncthreads();
  int val = s;
  for (int d=1; d<256; d<<=1){
    int other = (t>=d)? ts[t-d] : 0;
    __syncthreads();
    val += other; ts[t] = val;
    __syncthreads();
  }
  const int base = val - s;
  #pragma unroll
  for (int i=0;i<8;++i) off[t*8+i] = base + loc[i];
  if (t==255) off[2048] = val;
}

// ===================== K_wy: per-edge w = xW0/sqrt(128) and Y(l=0..3), stored sender-sorted =====================
__global__ __launch_bounds__(256) void k_wy(
    const float* __restrict__ vectors, const float* __restrict__ x,
    const int* __restrict__ senders, const float* __restrict__ W0,
    const int* __restrict__ pos, const int* __restrict__ off,
    float* __restrict__ w_sorted, float* __restrict__ Y_sorted)
{
  const int tid = threadIdx.x;
  const int lane = tid & 63;
  const int wv = tid >> 6;
  const int e = __builtin_amdgcn_readfirstlane((int)blockIdx.x*4 + wv);
  const int s = senders[e];
  const int p = off[s] + pos[e];          // unique slot within node segment

  const float* xr = x + e*128;            // wave-uniform -> scalar loads
  float sum = 0.f;
  #pragma unroll 16
  for (int k=0;k<128;++k) sum = fmaf(xr[k], W0[k*64+lane], sum);
  w_sorted[p*64 + lane] = sum * INV_SQRT_XD;

  const float vx = vectors[e*3+0], vy = vectors[e*3+1], vz = vectors[e*3+2];
  const float dn = sqrtf(vx*vx+vy*vy+vz*vz);
  const float ny[3] = {vy/dn, vz/dn, vx/dn};   // e3nn y,z,x basis
  float Y[16];
  Y[0] = 1.f; Y[1] = SQRT3F*ny[0]; Y[2] = SQRT3F*ny[1]; Y[3] = SQRT3F*ny[2];
  #pragma unroll
  for (int k=4;k<16;++k) Y[k] = 0.f;
  CONTRACT3(CG_112, 3,3,5, SHS.s0, (Y+1), ny, (Y+4));
  CONTRACT3(CG_213, 5,3,7, SHS.s1, (Y+4), ny, (Y+9));

  float yv = Y[0];
  #pragma unroll
  for (int k=1;k<16;++k) if (lane == k) yv = Y[k];
  if (lane < 16) Y_sorted[p*16 + lane] = yv;
}

// ===================== K_gather: per-node segment sum  node_sum[n,k,u] = 0.25 * sum_e Y[e,k] w[e,u] =====================
__global__ __launch_bounds__(256) void k_gather(
    const float* __restrict__ w_sorted, const float* __restrict__ Y_sorted,
    const int* __restrict__ off, float* __restrict__ node_sum)
{
  const int lane = threadIdx.x & 63;
  const int wv = threadIdx.x >> 6;
  const int n = __builtin_amdgcn_readfirstlane((int)blockIdx.x*4 + wv);
  const int p0 = off[n], p1 = off[n+1];
  float acc[16];
  #pragma unroll
  for (int k=0;k<16;++k) acc[k] = 0.f;
  for (int p=p0; p<p1; ++p){
    const float wu = w_sorted[p*64 + lane];
    const float* yr = Y_sorted + p*16;      // uniform -> scalar loads
    #pragma unroll
    for (int k=0;k<16;++k) acc[k] = fmaf(yr[k], wu, acc[k]);
  }
  float* dst = node_sum + n*1024;
  #pragma unroll
  for (int k=0;k<16;++k) dst[k*64 + lane] = acc[k] * INV_SQRT_NEI;
}

// ===================== K_main: gather + CG tensor products + fused bf16 MFMA GEMM =====================
// 4 edges/block, 4 M-tiles (40 KB LDS -> 4 blocks/CU):
//   ti0: x2 = [x | s0]       rows el=0..3              -> B = W1   (acc0)
//   ti1: v1 rows r=i*4+el    r=0..11                   -> B = Wl1  (acc1)
//   ti2: v2 rows r=i2*4+el   r=0..15                   -> B = Wl2  (acc2)
//   ti3: v2 rows 16..19      (i2=4)                    -> B = Wl2  (acc3)
// Garbage rows only affect D rows that are never stored.
DI void wr_frag(char* AF, int ti, int row, int m, float val){
  const int kt = m >> 5, q = (m >> 3) & 3, j = m & 7;
  *(unsigned short*)(AF + (((ti*10 + kt)*64 + row + (q<<4))<<4) + (j<<1)) = f2bf(val);
}

DI short8 load_bfrag_raw(const float* __restrict__ W, int kt, int nt, int lane){
  const int q = lane >> 4, c = lane & 15;
  const float* src = W + (kt*32 + q*8)*64 + nt*16 + c;
  short8 b;
  #pragma unroll
  for (int j=0;j<8;++j) b[j] = (short)f2bf(src[j*64]);
  return b;
}

__global__ __launch_bounds__(256,4) void k_main(
    const float* __restrict__ vectors, const float* __restrict__ x,
    const float* __restrict__ V, const int* __restrict__ senders,
    const float* __restrict__ W1, const float* __restrict__ W2,
    const float* __restrict__ W3, const float* __restrict__ Wl1,
    const float* __restrict__ Wl2, const float* __restrict__ node_sum,
    const short8* __restrict__ bfrag,
    float* __restrict__ out_x, float* __restrict__ out_V, float silu_c)
{
  __shared__ __align__(16) char smem[40960];   // 4 tiles * 10 kt * 1KB
  char*  AF  = smem;
  float* h1s = (float*)smem;                   // overlay after GEMM (guarded by barriers)
  float* h2s = (float*)(smem + 1024);

  const int tid  = threadIdx.x;
  const int lane = tid & 63;
  const int wv   = tid >> 6;
  const int blk  = blockIdx.x;

  // ---------------- Phase A: gather + tensor products + A-fragment staging (1 edge/wave) ----------------
  {
    const int el = wv;
    const int e  = __builtin_amdgcn_readfirstlane(blk*4 + el);
    const int s  = senders[e];
    const int u  = lane;

    float g[16];
    const float* nsrow = node_sum + s*1024;
    #pragma unroll
    for (int k=0;k<16;++k) g[k] = nsrow[k*64+u];       // 1/sqrt(16) folded into k_gather
    float vc[9];
    #pragma unroll
    for (int j=0;j<9;++j) vc[j] = V[e*576 + u*9 + j];

    float s0[3] = {0.f,0.f,0.f};
    float v1o[5][3] = {};
    float v2o[5][5] = {};
    CONTRACT3(CG_000, 1,1,1, 1.0, (g+0), (vc+0), (&s0[0]));
    CONTRACT3(CG_110, 3,3,1, 1.0, (g+1), (vc+1), (&s0[1]));
    CONTRACT3(CG_220, 5,5,1, 1.0, (g+4), (vc+4), (&s0[2]));
    CONTRACT3(CG_011, 1,3,3, SQ3D, (g+0), (vc+1), (v1o[0]));
    CONTRACT3(CG_101, 3,1,3, SQ3D, (g+1), (vc+0), (v1o[1]));
    CONTRACT3(CG_121, 3,5,3, SQ3D, (g+1), (vc+4), (v1o[2]));
    CONTRACT3(CG_211, 5,3,3, SQ3D, (g+4), (vc+1), (v1o[3]));
    CONTRACT3(CG_321, 7,5,3, SQ3D, (g+9), (vc+4), (v1o[4]));
    CONTRACT3(CG_022, 1,5,5, SQ5D, (g+0), (vc+4), (v2o[0]));
    CONTRACT3(CG_112, 3,3,5, SQ5D, (g+1), (vc+1), (v2o[1]));
    CONTRACT3(CG_202, 5,1,5, SQ5D, (g+4), (vc+0), (v2o[2]));
    CONTRACT3(CG_222, 5,5,5, SQ5D, (g+4), (vc+4), (v2o[3]));
    CONTRACT3(CG_312, 7,3,5, SQ5D, (g+9), (vc+1), (v2o[4]));

    wr_frag(AF, 0, el, u,      x[e*128 + u]);
    wr_frag(AF, 0, el, 64 + u, x[e*128 + 64 + u]);
    #pragma unroll
    for (int p=0;p<3;++p) wr_frag(AF, 0, el, 128 + u*3 + p, s0[p]);
    #pragma unroll
    for (int p=0;p<5;++p){
      const int m = u*5 + p;
      #pragma unroll
      for (int i=0;i<3;++i){ const int r = i*4+el; wr_frag(AF, 1, r, m, v1o[p][i]); }
      #pragma unroll
      for (int i=0;i<5;++i){ const int r = i*4+el; wr_frag(AF, 2+(r>>4), r&15, m, v2o[p][i]); }
    }
  }
  __syncthreads();

  // ---------------- GEMM: D = A(4 tiles x K320) * [W1|Wl1|Wl2], N-tile = wave ----------------
  f32x4 acc0={0.f,0.f,0.f,0.f}, acc1=acc0, acc2=acc0, acc3=acc0;
  const int nt = wv;
  for (int kt=0; kt<10; ++kt){
    short8 b0, b1, b2;
    if (bfrag != nullptr){
      b0 = bfrag[(( 0 + kt)*4 + nt)*64 + lane];
      b1 = bfrag[((10 + kt)*4 + nt)*64 + lane];
      b2 = bfrag[((20 + kt)*4 + nt)*64 + lane];
    } else {
      b0 = load_bfrag_raw(W1,  kt, nt, lane);
      b1 = load_bfrag_raw(Wl1, kt, nt, lane);
      b2 = load_bfrag_raw(Wl2, kt, nt, lane);
    }
    const char* ab = AF + kt*1024 + lane*16;
    const short8 a0 = *(const short8*)(ab);
    const short8 a1 = *(const short8*)(ab + 10240);
    const short8 a2 = *(const short8*)(ab + 20480);
    const short8 a3 = *(const short8*)(ab + 30720);
    acc0 = __builtin_amdgcn_mfma_f32_16x16x32_bf16(a0, b0, acc0, 0,0,0);
    acc1 = __builtin_amdgcn_mfma_f32_16x16x32_bf16(a1, b1, acc1, 0,0,0);
    acc2 = __builtin_amdgcn_mfma_f32_16x16x32_bf16(a2, b2, acc2, 0,0,0);
    acc3 = __builtin_amdgcn_mfma_f32_16x16x32_bf16(a3, b2, acc3, 0,0,0);
  }
  __syncthreads();   // all waves done reading AF before h1s overlays it

  // ---------------- Epilogue: equivariant stores + h1 into LDS ----------------
  // D layout: row = (lane>>4)*4 + reg, col = lane&15
  const int col = lane & 15, qq = lane >> 4;
  const int u2 = nt*16 + col;
  #pragma unroll
  for (int reg=0; reg<4; ++reg){
    const int row = qq*4 + reg;
    if (row < 4) h1s[row*64 + u2] = silu_n(acc0[reg] * INV320, silu_c);
    if (row < 12){ const int i = row>>2, ee = blk*4 + (row&3);
      out_V[ee*576 + 64 + u2*3 + i] = acc1[reg] * INV320; }
    { const int i2 = row>>2, ee = blk*4 + (row&3);
      out_V[ee*576 + 256 + u2*5 + i2] = acc2[reg] * INV320; }
    if (row < 4){ const int ee = blk*4 + row;
      out_V[ee*576 + 256 + u2*5 + 4] = acc3[reg] * INV320; }
  }
  __syncthreads();

  // ---------------- Scalar track: one edge per wave, j = lane ----------------
  const int e2 = blk*4 + wv;
  float sacc = 0.f;
  #pragma unroll 8
  for (int c=0;c<64;++c) sacc = fmaf(h1s[wv*64+c], W2[c*64+lane], sacc);
  h2s[wv*64 + lane] = silu_n(sacc * 0.125f, silu_c);
  __syncthreads();

  const float vx = vectors[e2*3+0], vy = vectors[e2*3+1], vz = vectors[e2*3+2];
  const float d  = sqrtf(vx*vx + vy*vy + vz*vz);
  const float d3 = d*d*d;
  const float d6 = d3*d3;
  const float env = (d < 1.f) ? (1.f + d6*(-28.f + d*(48.f + d*(-21.f)))) : 0.f;
  float sacc2 = 0.f;
  #pragma unroll 8
  for (int c=0;c<64;++c) sacc2 = fmaf(h2s[wv*64+c], W3[c*64+lane], sacc2);
  out_x[e2*64 + lane]  = env * (sacc2 * 0.125f);
  out_V[e2*576 + lane] = 0.f;             // zeros for the 64x0e slot
}

// ===================== host: normalized-silu constant (computed once at load) =====================
static const float g_silu_c = [](){
  const int N = 200001;
  const double h = 24.0/(double)(N-1);
  double acc = 0.0;
  for (int i=0;i<N;++i){
    const double z = -12.0 + h*(double)i;
    const double phi = std::exp(-z*z/2.0)/std::sqrt(2.0*M_PI);
    const double s = z/(1.0+std::exp(-z));
    const double f = s*s*phi;
    acc += (i==0 || i==N-1) ? 0.5*f : f;
  }
  return (float)(1.0/std::sqrt(acc*h));
}();

extern "C" void kernel_launch(void* const* d_in, const int* in_sizes, int n_in,
                              void* d_out, int out_size, void* d_ws, size_t ws_size,
                              hipStream_t stream) {
  (void)in_sizes; (void)n_in; (void)out_size;
  const float* vectors = (const float*)d_in[0];
  const float* x       = (const float*)d_in[1];
  const float* V       = (const float*)d_in[2];
  const int*   senders = (const int*)  d_in[3];
  const float* W0      = (const float*)d_in[4];
  const float* W1      = (const float*)d_in[5];
  const float* W2      = (const float*)d_in[6];
  const float* W3      = (const float*)d_in[7];
  const float* Wl1     = (const float*)d_in[8];
  const float* Wl2     = (const float*)d_in[9];
  float* out_x = (float*)d_out;
  float* out_V = out_x + (size_t)E_TOT*64;

  // Scratch inside d_out: all consumed by k_gather BEFORE k_main writes outputs (stream-ordered).
  char* ob = (char*)d_out;
  int*   pos      = (int*)(ob);                        // 128 KB
  int*   cnt      = (int*)(ob + 131072);               // 8 KB (memset)
  int*   off      = (int*)(ob + 139264);               // 8.2 KB
  float* w_sorted = (float*)(ob + 163840);             // 8 MB
  float* Y_sorted = (float*)(ob + 163840 + 8388608);   // 2 MB

  float* node_sum = (float*)d_ws;                      // 8 MB (fully written by k_gather)
  const size_t WS_NEED = (size_t)8*1024*1024 + 122880;
  short8* bfrag = (ws_size >= WS_NEED) ? (short8*)((char*)d_ws + 8*1024*1024) : nullptr;

  hipMemsetAsync(cnt, 0, 8192, stream);
  k_setup <<<dim3(158), dim3(256), 0, stream>>>(senders, pos, cnt, W1, Wl1, Wl2, bfrag);
  k_scan  <<<dim3(1),   dim3(256), 0, stream>>>(cnt, off);
  k_wy    <<<dim3(E_TOT/4), dim3(256), 0, stream>>>(vectors, x, senders, W0, pos, off, w_sorted, Y_sorted);
  k_gather<<<dim3(NNODE/4), dim3(256), 0, stream>>>(w_sorted, Y_sorted, off, node_sum);
  k_main  <<<dim3(E_TOT/4), dim3(256), 0, stream>>>(vectors, x, V, senders,
                                                    W1, W2, W3, Wl1, Wl2,
                                                    node_sum, bfrag, out_x, out_V, g_silu_c);
}

// Round 4
// 272.954 us; speedup vs baseline: 1.5127x; 1.1327x over previous
//
#include <hip/hip_runtime.h>
#include <cmath>
#include <utility>

#define DI __device__ __forceinline__

typedef __attribute__((ext_vector_type(8))) short  short8;
typedef __attribute__((ext_vector_type(4))) float  f32x4;

// ===================== constexpr Wigner-3j machinery (mirrors reference) =====================
constexpr double cfact(int n){ double r=1.0; for(int i=2;i<=n;++i) r*=(double)i; return r; }
constexpr double csqrt(double x){ if(x<=0.0) return 0.0; double g = x>1.0?x:1.0; for(int i=0;i<100;++i) g = 0.5*(g + x/g); return g; }
constexpr double csgn(int k){ int m = k%2; if(m<0) m+=2; return m? -1.0:1.0; }
constexpr int cmax3(int a,int b,int c){ int m=a>b?a:b; return m>c?m:c; }
constexpr int cmin3(int a,int b,int c){ int m=a<b?a:b; return m<c?m:c; }

struct cplx { double r, i; };
constexpr cplx cmul(cplx a, cplx b){ return cplx{a.r*b.r - a.i*b.i, a.r*b.i + a.i*b.r}; }
constexpr cplx cadd(cplx a, cplx b){ return cplx{a.r+b.r, a.i+b.i}; }
constexpr cplx cscale(cplx a, double s){ return cplx{a.r*s, a.i*s}; }
constexpr cplx cconj(cplx a){ return cplx{a.r, -a.i}; }

constexpr double su2_cg(int j1,int m1,int j2,int m2,int j3,int m3){
  if (m3 != m1+m2) return 0.0;
  const int vmin = cmax3(-j1+j2+m3, -j1+m1, 0);
  const int vmax = cmin3(j2+j3+m1, j3-j1+j2, j3+m3);
  const double c = csqrt((2.0*j3+1.0) * cfact(j3+j1-j2)*cfact(j3-j1+j2)*cfact(j1+j2-j3)/cfact(j1+j2+j3+1)
                         * cfact(j3+m3)*cfact(j3-m3)
                         / (cfact(j1+m1)*cfact(j1-m1)*cfact(j2+m2)*cfact(j2-m2)));
  double s = 0.0;
  for (int v=vmin; v<=vmax; ++v){
    s += csgn(v+j2+m2)/cfact(v)*cfact(j2+j3+m1-v)*cfact(j1-m1+v)
         /cfact(j3-j1+j2-v)/cfact(j3+m3-v)/cfact(v+j1-j2-m3);
  }
  return c*s;
}

template<int L> struct QM { cplx v[2*L+1][2*L+1]; };
template<int L> constexpr QM<L> qmat(){
  QM<L> q{};
  const double is2 = 0.70710678118654752440;
  for (int m=-L; m<0; ++m){
    q.v[L+m][L-m] = cplx{is2, 0.0};
    q.v[L+m][L+m] = cplx{0.0, -is2};
  }
  q.v[L][L] = cplx{1.0, 0.0};
  for (int m=1; m<=L; ++m){
    const double sg = (m%2)? -1.0 : 1.0;
    q.v[L+m][L+m] = cplx{sg*is2, 0.0};
    q.v[L+m][L-m] = cplx{0.0, sg*is2};
  }
  const cplx ph = (L%4==0)?cplx{1,0} : (L%4==1)?cplx{0,-1} : (L%4==2)?cplx{-1,0} : cplx{0,1};
  for (int a=0;a<2*L+1;++a) for(int b=0;b<2*L+1;++b) q.v[a][b] = cmul(ph, q.v[a][b]);
  return q;
}

template<int L1,int L2,int L3> struct W3J { float v[2*L1+1][2*L2+1][2*L3+1]; };

template<int L1,int L2,int L3> constexpr W3J<L1,L2,L3> w3j(){
  constexpr int N1=2*L1+1, N2=2*L2+1, N3=2*L3+1;
  double C[N1][N2][N3] = {};
  for (int m1=-L1;m1<=L1;++m1) for (int m2=-L2;m2<=L2;++m2){
    const int m3=m1+m2;
    if (m3>=-L3 && m3<=L3) C[L1+m1][L2+m2][L3+m3] = su2_cg(L1,m1,L2,m2,L3,m3);
  }
  const QM<L1> q1 = qmat<L1>(); const QM<L2> q2 = qmat<L2>(); const QM<L3> q3 = qmat<L3>();
  cplx T1[N1][N2][N3] = {};
  for(int j=0;j<N1;++j) for(int k=0;k<N2;++k) for(int m=0;m<N3;++m){
    cplx acc{0,0};
    for(int i=0;i<N1;++i) acc = cadd(acc, cscale(q1.v[i][j], C[i][k][m]));
    T1[j][k][m]=acc;
  }
  cplx T2[N1][N2][N3] = {};
  for(int j=0;j<N1;++j) for(int l=0;l<N2;++l) for(int m=0;m<N3;++m){
    cplx acc{0,0};
    for(int k=0;k<N2;++k) acc = cadd(acc, cmul(q2.v[k][l], T1[j][k][m]));
    T2[j][l][m]=acc;
  }
  double O[N1][N2][N3] = {};
  double fro = 0.0;
  for(int j=0;j<N1;++j) for(int l=0;l<N2;++l) for(int n=0;n<N3;++n){
    cplx acc{0,0};
    for(int m=0;m<N3;++m) acc = cadd(acc, cmul(cconj(q3.v[m][n]), T2[j][l][m]));
    O[j][l][n] = acc.r;
    fro += acc.r*acc.r;
  }
  const double inv = 1.0/csqrt(fro);
  W3J<L1,L2,L3> w{};
  for(int j=0;j<N1;++j) for(int l=0;l<N2;++l) for(int n=0;n<N3;++n)
    w.v[j][l][n] = (float)(O[j][l][n]*inv);
  return w;
}

constexpr auto CG_000 = w3j<0,0,0>();
constexpr auto CG_110 = w3j<1,1,0>();
constexpr auto CG_220 = w3j<2,2,0>();
constexpr auto CG_011 = w3j<0,1,1>();
constexpr auto CG_101 = w3j<1,0,1>();
constexpr auto CG_121 = w3j<1,2,1>();
constexpr auto CG_211 = w3j<2,1,1>();
constexpr auto CG_321 = w3j<3,2,1>();
constexpr auto CG_022 = w3j<0,2,2>();
constexpr auto CG_112 = w3j<1,1,2>();
constexpr auto CG_202 = w3j<2,0,2>();
constexpr auto CG_222 = w3j<2,2,2>();
constexpr auto CG_312 = w3j<3,1,2>();
constexpr auto CG_213 = w3j<2,1,3>();   // SH recursion l=2 -> l=3

struct ShS { double s0, s1; };
constexpr ShS sh_scales(){
  const double n0=0.3,n1=0.5,n2=0.81;
  const double nn = csqrt(n0*n0+n1*n1+n2*n2);
  const double ny[3] = {n1/nn, n2/nn, n0/nn};
  const double sq3 = csqrt(3.0);
  double Y1[3]; for(int i=0;i<3;++i) Y1[i] = sq3*ny[i];
  double A[5] = {};
  for(int i=0;i<3;++i) for(int j=0;j<3;++j) for(int k=0;k<5;++k)
    A[k] += Y1[i]*ny[j]*(double)CG_112.v[i][j][k];
  double na=0; for(int k=0;k<5;++k) na += A[k]*A[k]; na = csqrt(na);
  const double s0 = csqrt(5.0)/na;
  double Y2[5]; for(int k=0;k<5;++k) Y2[k] = A[k]*s0;
  double B[7] = {};
  for(int i=0;i<5;++i) for(int j=0;j<3;++j) for(int k=0;k<7;++k)
    B[k] += Y2[i]*ny[j]*(double)CG_213.v[i][j][k];
  double nb=0; for(int k=0;k<7;++k) nb += B[k]*B[k]; nb = csqrt(nb);
  const double s1 = csqrt(7.0)/nb;
  return ShS{s0,s1};
}
constexpr ShS SHS = sh_scales();

// ===================== static-for + zero-skipping contraction =====================
template<typename F, int... Is>
DI void sfor_impl(F&& f, std::integer_sequence<int, Is...>){ (f(std::integral_constant<int,Is>{}), ...); }
template<int N, typename F>
DI void sfor(F&& f){ sfor_impl(f, std::make_integer_sequence<int, N>{}); }

template<int N>
__host__ __device__ constexpr bool col_any(const float (&c)[N]){
  for(int k=0;k<N;++k) if (c[k]!=0.0f) return true;
  return false;
}

#define CONTRACT3(TAB, NI, NJ, NK, SCALE, INI, INJ, OUT) \
  sfor<(NI)>([&](auto I__){ constexpr int i__ = decltype(I__)::value; \
    sfor<(NJ)>([&](auto J__){ constexpr int j__ = decltype(J__)::value; \
      if constexpr (col_any((TAB).v[i__][j__])) { \
        const float t__ = (INI)[i__] * (INJ)[j__]; \
        sfor<(NK)>([&](auto K__){ constexpr int k__ = decltype(K__)::value; \
          if constexpr ((TAB).v[i__][j__][k__] != 0.0f) { \
            constexpr float c__ = (float)((double)(TAB).v[i__][j__][k__] * (double)(SCALE)); \
            (OUT)[k__] = fmaf(c__, t__, (OUT)[k__]); \
          } }); } }); });

// ===================== device helpers =====================
DI unsigned short f2bf(float f){            // round-to-nearest-even fp32 -> bf16
  unsigned int u = __float_as_uint(f);
  u += 0x7fffu + ((u >> 16) & 1u);
  return (unsigned short)(u >> 16);
}
DI float silu_n(float z, float c){ return c * (z / (1.0f + __expf(-z))); }

constexpr float SQRT3F        = (float)csqrt(3.0);
constexpr double SQ3D         = csqrt(3.0);
constexpr double SQ5D         = csqrt(5.0);
constexpr float INV_SQRT_XD   = (float)(1.0/csqrt(128.0));
constexpr float INV_SQRT_NEI  = 0.25f;                    // 1/sqrt(16)
constexpr float INV320        = (float)(1.0/csqrt(320.0));

constexpr int E_TOT = 32768;
constexpr int NNODE = 2048;

// B-fragment raw loader (B[k][n] for 16x16x32: lane(q,c) holds k=q*8+j, n=c); 64-col matrices
DI short8 load_bfrag_raw(const float* __restrict__ W, int kt, int nt, int lane){
  const int q = lane >> 4, c = lane & 15;
  const float* src = W + (kt*32 + q*8)*64 + nt*16 + c;
  short8 b;
  #pragma unroll
  for (int j=0;j<8;++j) b[j] = (short)f2bf(src[j*64]);
  return b;
}

// ===================== K_setup: B-fragment precompute (blocks 0..33) + sender histogram =====================
// wid 0..15:  W0  (kt=wid>>2, nt=wid&3)
// wid 16..55: W1 ; 56..95: Wl1 ; 96..135: Wl2  (kt=r>>2, nt=r&3)
__global__ __launch_bounds__(256) void k_setup(
    const int* __restrict__ senders, int* __restrict__ pos, int* __restrict__ cnt,
    const float* __restrict__ W0, const float* __restrict__ W1,
    const float* __restrict__ Wl1, const float* __restrict__ Wl2,
    short8* __restrict__ bfrag)
{
  const int blk = blockIdx.x;
  if (blk < 34){
    if (bfrag == nullptr) return;
    const int wv = threadIdx.x >> 6, lane = threadIdx.x & 63;
    const int wid = blk*4 + wv;
    if (wid >= 136) return;
    const float* W; int kt, nt;
    if (wid < 16){ W = W0; kt = wid>>2; nt = wid&3; }
    else { const int t = wid-16; const int mat = t/40, r = t%40;
           W = (mat==0)?W1 : (mat==1)?Wl1 : Wl2; kt = r>>2; nt = r&3; }
    bfrag[wid*64 + lane] = load_bfrag_raw(W, kt, nt, lane);
  } else {
    const int e = (blk-34)*256 + threadIdx.x;
    if (e < E_TOT) pos[e] = atomicAdd(&cnt[senders[e]], 1);
  }
}

// ===================== K_scan: exclusive prefix over 2048 counts (1 block) =====================
__global__ __launch_bounds__(256) void k_scan(const int* __restrict__ cnt, int* __restrict__ off)
{
  __shared__ int ts[256];
  const int t = threadIdx.x;
  int loc[8]; int s = 0;
  #pragma unroll
  for (int i=0;i<8;++i){ int v = cnt[t*8+i]; loc[i] = s; s += v; }
  ts[t] = s;
  __syncthreads();
  int val = s;
  for (int d=1; d<256; d<<=1){
    int other = (t>=d)? ts[t-d] : 0;
    __syncthreads();
    val += other; ts[t] = val;
    __syncthreads();
  }
  const int base = val - s;
  #pragma unroll
  for (int i=0;i<8;++i) off[t*8+i] = base + loc[i];
  if (t==255) off[2048] = val;
}

// ===================== K_wy: MFMA w = xW0/sqrt(128) (unsorted) + Y + sorted eid list =====================
// 64 edges/block; wave wv: M-tile = edges e0+16wv..+15, D(16x64) = x_tile(16x128) @ W0(128x64).
__global__ __launch_bounds__(256) void k_wy(
    const float* __restrict__ vectors, const float* __restrict__ x,
    const int* __restrict__ senders, const float* __restrict__ W0,
    const int* __restrict__ pos, const int* __restrict__ off,
    const short8* __restrict__ bfrag,
    float* __restrict__ w_un, float* __restrict__ Y_un, int* __restrict__ eids)
{
  const int tid = threadIdx.x, lane = tid & 63, wv = tid >> 6;
  const int e0 = blockIdx.x * 64;
  const int r = lane & 15, q = lane >> 4;
  const int erow = e0 + wv*16 + r;

  f32x4 acc[4] = {{0.f,0.f,0.f,0.f},{0.f,0.f,0.f,0.f},{0.f,0.f,0.f,0.f},{0.f,0.f,0.f,0.f}};
  #pragma unroll
  for (int kt=0; kt<4; ++kt){
    const float4* xp = (const float4*)(x + (size_t)erow*128 + kt*32 + q*8);
    const float4 xa = xp[0], xb = xp[1];
    short8 a;
    a[0]=(short)f2bf(xa.x); a[1]=(short)f2bf(xa.y); a[2]=(short)f2bf(xa.z); a[3]=(short)f2bf(xa.w);
    a[4]=(short)f2bf(xb.x); a[5]=(short)f2bf(xb.y); a[6]=(short)f2bf(xb.z); a[7]=(short)f2bf(xb.w);
    #pragma unroll
    for (int nt=0; nt<4; ++nt){
      const short8 b = (bfrag != nullptr) ? bfrag[(kt*4+nt)*64 + lane]
                                          : load_bfrag_raw(W0, kt, nt, lane);
      acc[nt] = __builtin_amdgcn_mfma_f32_16x16x32_bf16(a, b, acc[nt], 0,0,0);
    }
  }
  #pragma unroll
  for (int nt=0; nt<4; ++nt)
    #pragma unroll
    for (int reg=0; reg<4; ++reg){
      const int row = q*4 + reg;                     // C/D: row=(lane>>4)*4+reg, col=lane&15
      w_un[(size_t)(e0 + wv*16 + row)*64 + nt*16 + r] = acc[nt][reg] * INV_SQRT_XD;
    }

  // Y + sorted-eid phase (one thread per edge)
  if (tid < 64){
    const int e = e0 + tid;
    const float vx = vectors[e*3+0], vy = vectors[e*3+1], vz = vectors[e*3+2];
    const float dn = sqrtf(vx*vx+vy*vy+vz*vz);
    const float ny[3] = {vy/dn, vz/dn, vx/dn};       // e3nn y,z,x basis
    float Y[16];
    Y[0] = 1.f; Y[1] = SQRT3F*ny[0]; Y[2] = SQRT3F*ny[1]; Y[3] = SQRT3F*ny[2];
    #pragma unroll
    for (int k=4;k<16;++k) Y[k] = 0.f;
    CONTRACT3(CG_112, 3,3,5, SHS.s0, (Y+1), ny, (Y+4));
    CONTRACT3(CG_213, 5,3,7, SHS.s1, (Y+4), ny, (Y+9));
    #pragma unroll
    for (int k=0;k<16;++k) Y_un[e*16+k] = Y[k];
    const int s = senders[e];
    eids[off[s] + pos[e]] = e;
  }
}

// ===================== K_gather: per-node segment sum via sorted eid list =====================
__global__ __launch_bounds__(256) void k_gather(
    const float* __restrict__ w_un, const float* __restrict__ Y_un,
    const int* __restrict__ off, const int* __restrict__ eids,
    float* __restrict__ node_sum)
{
  const int lane = threadIdx.x & 63;
  const int wv = threadIdx.x >> 6;
  const int n = __builtin_amdgcn_readfirstlane((int)blockIdx.x*4 + wv);
  const int p0 = off[n], p1 = off[n+1];
  float acc[16];
  #pragma unroll
  for (int k=0;k<16;++k) acc[k] = 0.f;
  for (int p=p0; p<p1; ++p){
    const int eid = eids[p];                 // wave-uniform -> scalar load
    const float wu = w_un[(size_t)eid*64 + lane];
    const float* yr = Y_un + eid*16;         // uniform -> scalar loads
    #pragma unroll
    for (int k=0;k<16;++k) acc[k] = fmaf(yr[k], wu, acc[k]);
  }
  float* dst = node_sum + n*1024;
  #pragma unroll
  for (int k=0;k<16;++k) dst[k*64 + lane] = acc[k] * INV_SQRT_NEI;
}

// ===================== K_main: gather + CG tensor products + fused bf16 MFMA GEMM =====================
// 4 edges/block, 4 M-tiles, 40 KB LDS -> 4 blocks/CU.
// A staged row-major bf16: byte addr = ((tile*10+kt)*16 + row)*64 + (m&31)*2  (kt = m>>5)
// A-frag read = single ds_read_b128 at (lane&15)*64 + (lane>>4)*16 (bank-balanced).
DI void wr2(char* AF, int tile, int row, int m, float val){
  const int kt = m >> 5, m0 = m & 31;
  *(unsigned short*)(AF + (((tile*10 + kt)*16 + row)<<6) + (m0<<1)) = f2bf(val);
}

__global__ __launch_bounds__(256,4) void k_main(
    const float* __restrict__ vectors, const float* __restrict__ x,
    const float* __restrict__ V, const int* __restrict__ senders,
    const float* __restrict__ W1, const float* __restrict__ W2,
    const float* __restrict__ W3, const float* __restrict__ Wl1,
    const float* __restrict__ Wl2, const float* __restrict__ node_sum,
    const short8* __restrict__ bfrag,
    float* __restrict__ out_x, float* __restrict__ out_V, float silu_c)
{
  __shared__ __align__(16) char smem[40960];   // 4 tiles * 10 kt * 16 rows * 64 B
  char*  AF    = smem;
  float* h1s   = (float*)smem;                 // [0,1024)   overlay after GEMM
  float* h2s   = (float*)(smem + 1024);        // [1024,2048)
  float* stage = (float*)(smem + 2048);        // [2048,11264): 4 edges x 576 floats

  const int tid  = threadIdx.x;
  const int lane = tid & 63;
  const int wv   = tid >> 6;
  const int blk  = blockIdx.x;

  // ---------------- Phase A: gather + tensor products + A staging (1 edge/wave) ----------------
  {
    const int el = wv;
    const int e  = __builtin_amdgcn_readfirstlane(blk*4 + el);
    const int s  = senders[e];
    const int u  = lane;

    // V row: coalesced global -> LDS -> per-lane redistribute (own-wave scratch, pre-barrier)
    float* smV = (float*)(smem + wv*2304);
    #pragma unroll
    for (int j=0;j<9;++j) smV[j*64 + lane] = V[(size_t)e*576 + j*64 + lane];
    float vc[9];
    #pragma unroll
    for (int j=0;j<9;++j) vc[j] = smV[u*9 + j];

    float g[16];
    const float* nsrow = node_sum + s*1024;
    #pragma unroll
    for (int k=0;k<16;++k) g[k] = nsrow[k*64+u];       // 1/sqrt(16) folded into k_gather
    const float x0 = x[(size_t)e*128 + u];
    const float x1 = x[(size_t)e*128 + 64 + u];

    __syncthreads();   // all smV reads done before any wave writes fragments

    float s0[3] = {0.f,0.f,0.f};
    float v1o[5][3] = {};
    float v2o[5][5] = {};
    CONTRACT3(CG_000, 1,1,1, 1.0, (g+0), (vc+0), (&s0[0]));
    CONTRACT3(CG_110, 3,3,1, 1.0, (g+1), (vc+1), (&s0[1]));
    CONTRACT3(CG_220, 5,5,1, 1.0, (g+4), (vc+4), (&s0[2]));
    CONTRACT3(CG_011, 1,3,3, SQ3D, (g+0), (vc+1), (v1o[0]));
    CONTRACT3(CG_101, 3,1,3, SQ3D, (g+1), (vc+0), (v1o[1]));
    CONTRACT3(CG_121, 3,5,3, SQ3D, (g+1), (vc+4), (v1o[2]));
    CONTRACT3(CG_211, 5,3,3, SQ3D, (g+4), (vc+1), (v1o[3]));
    CONTRACT3(CG_321, 7,5,3, SQ3D, (g+9), (vc+4), (v1o[4]));
    CONTRACT3(CG_022, 1,5,5, SQ5D, (g+0), (vc+4), (v2o[0]));
    CONTRACT3(CG_112, 3,3,5, SQ5D, (g+1), (vc+1), (v2o[1]));
    CONTRACT3(CG_202, 5,1,5, SQ5D, (g+4), (vc+0), (v2o[2]));
    CONTRACT3(CG_222, 5,5,5, SQ5D, (g+4), (vc+4), (v2o[3]));
    CONTRACT3(CG_312, 7,3,5, SQ5D, (g+9), (vc+1), (v2o[4]));

    wr2(AF, 0, el, u,      x0);
    wr2(AF, 0, el, 64 + u, x1);
    #pragma unroll
    for (int p=0;p<3;++p) wr2(AF, 0, el, 128 + u*3 + p, s0[p]);
    #pragma unroll
    for (int p=0;p<5;++p){
      const int m = u*5 + p;
      #pragma unroll
      for (int i=0;i<3;++i){ const int rr = i*4+el; wr2(AF, 1, rr, m, v1o[p][i]); }
      #pragma unroll
      for (int i=0;i<5;++i){ const int rr = i*4+el; wr2(AF, 2+(rr>>4), rr&15, m, v2o[p][i]); }
    }
  }
  __syncthreads();

  // ---------------- GEMM: D = A(4 tiles x K320) * [W1|Wl1|Wl2], N-tile = wave ----------------
  f32x4 acc0={0.f,0.f,0.f,0.f}, acc1=acc0, acc2=acc0, acc3=acc0;
  const int nt = wv;
  const int aoff = (lane&15)*64 + (lane>>4)*16;
  for (int kt=0; kt<10; ++kt){
    short8 b0, b1, b2;
    if (bfrag != nullptr){
      b0 = bfrag[(16 + kt*4 + nt)*64 + lane];
      b1 = bfrag[(56 + kt*4 + nt)*64 + lane];
      b2 = bfrag[(96 + kt*4 + nt)*64 + lane];
    } else {
      b0 = load_bfrag_raw(W1,  kt, nt, lane);
      b1 = load_bfrag_raw(Wl1, kt, nt, lane);
      b2 = load_bfrag_raw(Wl2, kt, nt, lane);
    }
    const char* ab = AF + kt*1024 + aoff;
    const short8 a0 = *(const short8*)(ab);
    const short8 a1 = *(const short8*)(ab + 10240);
    const short8 a2 = *(const short8*)(ab + 20480);
    const short8 a3 = *(const short8*)(ab + 30720);
    acc0 = __builtin_amdgcn_mfma_f32_16x16x32_bf16(a0, b0, acc0, 0,0,0);
    acc1 = __builtin_amdgcn_mfma_f32_16x16x32_bf16(a1, b1, acc1, 0,0,0);
    acc2 = __builtin_amdgcn_mfma_f32_16x16x32_bf16(a2, b2, acc2, 0,0,0);
    acc3 = __builtin_amdgcn_mfma_f32_16x16x32_bf16(a3, b2, acc3, 0,0,0);
  }
  __syncthreads();   // all waves done reading AF before overlays

  // ---------------- Epilogue: stage equivariant rows in LDS + h1 ----------------
  // D layout: row = (lane>>4)*4 + reg, col = lane&15
  const int col = lane & 15, qq = lane >> 4;
  const int u2 = nt*16 + col;
  stage[qq*576 + u2] = 0.f;                    // 64x0e zero slot (edge=qq)
  #pragma unroll
  for (int reg=0; reg<4; ++reg){
    const int row = qq*4 + reg;
    if (row < 4) h1s[row*64 + u2] = silu_n(acc0[reg] * INV320, silu_c);
    if (row < 12){ const int i = row>>2, ee = row&3;
      stage[ee*576 + 64 + u2*3 + i] = acc1[reg] * INV320; }
    { const int i2 = row>>2, ee = row&3;
      stage[ee*576 + 256 + u2*5 + i2] = acc2[reg] * INV320; }
    if (row < 4){
      stage[row*576 + 256 + u2*5 + 4] = acc3[reg] * INV320; }
  }
  __syncthreads();

  // ---------------- Scalar track (edge = wv, j = lane) + coalesced V-row store ----------------
  const int e2 = blk*4 + wv;
  float sacc = 0.f;
  #pragma unroll 8
  for (int c=0;c<64;++c) sacc = fmaf(h1s[wv*64+c], W2[c*64+lane], sacc);
  h2s[wv*64 + lane] = silu_n(sacc * 0.125f, silu_c);
  __syncthreads();

  const float vx = vectors[e2*3+0], vy = vectors[e2*3+1], vz = vectors[e2*3+2];
  const float d  = sqrtf(vx*vx + vy*vy + vz*vz);
  const float d3 = d*d*d;
  const float d6 = d3*d3;
  const float env = (d < 1.f) ? (1.f + d6*(-28.f + d*(48.f + d*(-21.f)))) : 0.f;
  float sacc2 = 0.f;
  #pragma unroll 8
  for (int c=0;c<64;++c) sacc2 = fmaf(h2s[wv*64+c], W3[c*64+lane], sacc2);
  out_x[(size_t)e2*64 + lane] = env * (sacc2 * 0.125f);

  const float* st = stage + wv*576;
  #pragma unroll
  for (int j=0;j<9;++j) out_V[(size_t)e2*576 + j*64 + lane] = st[j*64 + lane];
}

// ===================== host: normalized-silu constant (computed once at load) =====================
static const float g_silu_c = [](){
  const int N = 200001;
  const double h = 24.0/(double)(N-1);
  double acc = 0.0;
  for (int i=0;i<N;++i){
    const double z = -12.0 + h*(double)i;
    const double phi = std::exp(-z*z/2.0)/std::sqrt(2.0*M_PI);
    const double s = z/(1.0+std::exp(-z));
    const double f = s*s*phi;
    acc += (i==0 || i==N-1) ? 0.5*f : f;
  }
  return (float)(1.0/std::sqrt(acc*h));
}();

extern "C" void kernel_launch(void* const* d_in, const int* in_sizes, int n_in,
                              void* d_out, int out_size, void* d_ws, size_t ws_size,
                              hipStream_t stream) {
  (void)in_sizes; (void)n_in; (void)out_size;
  const float* vectors = (const float*)d_in[0];
  const float* x       = (const float*)d_in[1];
  const float* V       = (const float*)d_in[2];
  const int*   senders = (const int*)  d_in[3];
  const float* W0      = (const float*)d_in[4];
  const float* W1      = (const float*)d_in[5];
  const float* W2      = (const float*)d_in[6];
  const float* W3      = (const float*)d_in[7];
  const float* Wl1     = (const float*)d_in[8];
  const float* Wl2     = (const float*)d_in[9];
  float* out_x = (float*)d_out;
  float* out_V = out_x + (size_t)E_TOT*64;

  // Scratch inside d_out: all consumed by k_gather BEFORE k_main writes outputs (stream-ordered).
  // NOTE: off holds 2049 ints (8196 B) -> give it 12 KB. (R3 bug: off[2048] aliased eids[0].)
  char* ob = (char*)d_out;
  int*   pos   = (int*)(ob);                          // [0, 128 KB)
  int*   cnt   = (int*)(ob + 131072);                 // [128 KB, 136 KB)  (memset)
  int*   off   = (int*)(ob + 139264);                 // [136 KB, 148 KB)  2049 ints
  int*   eids  = (int*)(ob + 151552);                 // [148 KB, 276 KB)
  float* w_un  = (float*)(ob + 282624);               // [276 KB, +8 MB)
  float* Y_un  = (float*)(ob + 282624 + 8388608);     // [+8 MB, +10 MB)

  float* node_sum = (float*)d_ws;                     // 8 MB (fully written by k_gather)
  const size_t WS_NEED = (size_t)8*1024*1024 + 136*1024;
  short8* bfrag = (ws_size >= WS_NEED) ? (short8*)((char*)d_ws + 8*1024*1024) : nullptr;

  hipMemsetAsync(cnt, 0, 8192, stream);
  k_setup <<<dim3(162), dim3(256), 0, stream>>>(senders, pos, cnt, W0, W1, Wl1, Wl2, bfrag);
  k_scan  <<<dim3(1),   dim3(256), 0, stream>>>(cnt, off);
  k_wy    <<<dim3(E_TOT/64), dim3(256), 0, stream>>>(vectors, x, senders, W0, pos, off, bfrag, w_un, Y_un, eids);
  k_gather<<<dim3(NNODE/4),  dim3(256), 0, stream>>>(w_un, Y_un, off, eids, node_sum);
  k_main  <<<dim3(E_TOT/4),  dim3(256), 0, stream>>>(vectors, x, V, senders,
                                                     W1, W2, W3, Wl1, Wl2,
                                                     node_sum, bfrag, out_x, out_V, g_silu_c);
}